// Round 6
// baseline (203.861 us; speedup 1.0000x reference)
//
#include <hip/hip_runtime.h>
#include <stdint.h>

// EnergyWell, round 6: row-per-instance (16 lanes), perfectly-coalesced avail.
//
// R5 post-mortem: kernel pinned ~53us regardless of VALU work; effective read
// rate 2.6 TB/s vs 6.9 TB/s fill rate. Suspect: per-instruction address
// divergence — R5's avail loads touched 64 distinct cache lines per VMEM
// instruction (one per lane), 4x the coalesced minimum, throttling the
// per-CU L1/TA line-transaction rate. This version:
//  - avail read: lane L loads avail4[tile*256 + 64j + L] — 16B/lane
//    contiguous, 1KB/instr, 16 lines/instr (hardware minimum).
//    Index algebra: L = 16g+q -> instance base+4j+g, wells 4q..4q+3, so each
//    16-lane ROW owns one instance per j.
//  - row reduction on the VALU pipe: DPP row_ror 1/2/4/8 + fminf (rows of 16
//    are exactly the DPP row size; no LDS pipe, no 64-bit keys).
//  - tie-break: lowest lane achieving row-min (ballot) = lowest q = lowest
//    well c; within lane, lowest t. Exact jnp.argmin first-index semantics.

#define C_WELLS 64

template <int CTRL>
__device__ __forceinline__ float fmin_dpp(float v) {
    const float o = __uint_as_float(__builtin_amdgcn_update_dpp(
        0, (int)__float_as_uint(v), CTRL, 0xF, 0xF, true));
    return fminf(v, o);
}

__global__ __launch_bounds__(256, 6)
void energy_well_kernel(const float2* __restrict__ inst_pos,   // N
                        const float2* __restrict__ half_sizes, // N
                        const float*  __restrict__ well_boxes, // 64*4 {xl,yl,xh,yh}
                        const int4*   __restrict__ avail4,     // N*16
                        const float*  __restrict__ exponents,  // N
                        float* __restrict__ out,               // N
                        int N, int nT16)
{
    const int lane = threadIdx.x & 63;
    const int q    = lane & 15;      // quarter: wells 4q..4q+3 of the row's instance
    const int g    = lane >> 4;      // row id: instance subgroup 0..3
    const int tile = (int)((blockIdx.x * blockDim.x + threadIdx.x) >> 6);
    if (tile >= nT16) return;        // wave-uniform
    const int base = tile << 4;

    // ---- all loads issued up front, independent ----
    // avail: 4 instrs, each 1KB contiguous (16 cache lines — minimum possible)
    const size_t idx0 = (size_t)tile * 256 + (size_t)lane;
    const size_t last = (size_t)N * 16 - 1;
    int4 av[4];
    #pragma unroll
    for (int j = 0; j < 4; ++j) {
        const size_t idx = idx0 + (size_t)(64 * j);
        av[j] = avail4[idx <= last ? idx : last];   // clamp (partial-tail safety)
    }
    // per-row instance scalars (16 lanes share each address -> broadcast loads)
    float2 pj[4], hj[4]; float ej[4];
    #pragma unroll
    for (int j = 0; j < 4; ++j) {
        const int i  = base + 4 * j + g;
        const int ii = i < N ? i : N - 1;
        pj[j] = inst_pos[ii];
        hj[j] = half_sizes[ii];
        ej[j] = exponents[ii];
    }
    // this lane's y-row edges (iy = q>>1): 2 per-lane loads, 8 distinct addrs
    const int iy = q >> 1;
    const float ylq = well_boxes[32 * iy + 1];
    const float yhq = well_boxes[32 * iy + 3];

    // x-edges: wave-uniform s_loads; materialize this lane's 4 via cndmask
    float xlv[8], xhv[8];
    #pragma unroll
    for (int ix = 0; ix < 8; ++ix) {
        xlv[ix] = well_boxes[4 * ix + 0];
        xhv[ix] = well_boxes[4 * ix + 2];
    }
    const bool hiHalf = (q & 1) != 0;   // wells 4q..: ix = 4*(q&1)+t
    float xlq[4], xhq[4];
    #pragma unroll
    for (int t = 0; t < 4; ++t) {
        xlq[t] = hiHalf ? xlv[4 + t] : xlv[t];
        xhq[t] = hiHalf ? xhv[4 + t] : xhv[t];
    }

    // ---- 4 instances per row, one per j ----
    #pragma unroll
    for (int j = 0; j < 4; ++j) {
        const int i = base + 4 * j + g;
        const float xm = pj[j].x - hj[j].x, xp_ = pj[j].x + hj[j].x;
        const float ym = pj[j].y - hj[j].y, yp_ = pj[j].y + hj[j].y;
        const float dy = fmaxf(fmaxf(ylq - ym, yp_ - yhq), 0.0f);   // v_max3

        const int4 a4 = av[j];
        float dx[4], dist[4];
        #pragma unroll
        for (int t = 0; t < 4; ++t) {
            dx[t] = fmaxf(fmaxf(xlq[t] - xm, xp_ - xhq[t]), 0.0f);
            const int avw = (t == 0) ? a4.x : (t == 1) ? a4.y
                          : (t == 2) ? a4.z : a4.w;
            dist[t] = avw ? (dx[t] + dy) : __builtin_inff();
        }
        const float lmin = fminf(fminf(dist[0], dist[1]),
                                 fminf(dist[2], dist[3]));

        // row-of-16 min, VALU pipe only (DPP rotations within the row)
        float rmin = lmin;
        rmin = fmin_dpp<0x121>(rmin);   // row_ror:1
        rmin = fmin_dpp<0x122>(rmin);   // row_ror:2
        rmin = fmin_dpp<0x124>(rmin);   // row_ror:4
        rmin = fmin_dpp<0x128>(rmin);   // row_ror:8

        // winner = lowest lane in the row achieving rmin (=> lowest well c)
        const unsigned long long b = __ballot(lmin == rmin);
        const unsigned rowmask = (unsigned)((b >> (lane & 48)) & 0xFFFFull);
        const int wq = __ffs(rowmask) - 1;

        if ((q == wq) && (i < N)) {
            // lowest t achieving the min within this lane (dist masked to inf
            // on unavailable wells, so equality implies available)
            float dxs = dx[3];
            dxs = (dist[2] == rmin) ? dx[2] : dxs;
            dxs = (dist[1] == rmin) ? dx[1] : dxs;
            dxs = (dist[0] == rmin) ? dx[0] : dxs;
            const float e = ej[j];
            float energy;
            if (e == 2.0f) energy = dxs * dxs + dy * dy;
            else           energy = powf(dxs, e) + powf(dy, e);
            out[i] = energy;
        }
    }
}

extern "C" void kernel_launch(void* const* d_in, const int* in_sizes, int n_in,
                              void* d_out, int out_size, void* d_ws, size_t ws_size,
                              hipStream_t stream)
{
    // 0: inst_pos (N*2 f32), 1: half_inst_sizes (N*2 f32), 2: inst_areas (UNUSED),
    // 3: well_boxes (64*4 f32), 4: inst_cr_avail_map (N*64 int), 5: exponents (N)
    const float2* inst_pos   = (const float2*)d_in[0];
    const float2* half_sizes = (const float2*)d_in[1];
    const float*  well_boxes = (const float*)d_in[3];
    const int4*   avail4     = (const int4*)d_in[4];
    const float*  exponents  = (const float*)d_in[5];
    float* out = (float*)d_out;

    const int N = in_sizes[5];
    const int nT16 = (N + 15) / 16;          // one 16-instance tile per wave
    const int blocks = (nT16 + 3) / 4;       // 4 waves/block

    energy_well_kernel<<<dim3(blocks), dim3(256), 0, stream>>>(
        inst_pos, half_sizes, well_boxes, avail4, exponents, out, N, nT16);
}

// Round 7
// 192.258 us; speedup vs baseline: 1.0604x; 1.0604x over previous
//
#include <hip/hip_runtime.h>
#include <stdint.h>

// EnergyWell, round 7: R5 structure (quad-per-instance, 64-bit-key argmin,
// DPP quad reduce) with max occupancy — the read-ceiling falsification probe.
//
// R6 post-mortem: perfect coalescing regressed (61us vs 53) -> line-divergence
// theory dead. R4-R6 all pin at ~2.6 TB/s effective read regardless of VALU
// count, layout, or persistence; Little's law says MLP is ample. Hypothesis:
// L2-miss streaming-read path (XCD<->IOD fabric, ~128B/cyc/XCD = 2.46 TB/s)
// is the structural ceiling. This round: __launch_bounds__(256,8) (64-VGPR
// cap -> 32 waves/CU, 1.33x in-flight) + register-trimmed key scan (2 chains
// of 8). If time stays ~53us, we're at the roofline.

#define C_WELLS 64

template <int CTRL>
__device__ __forceinline__ unsigned long long dpp64(unsigned long long k) {
    int lo = (int)(unsigned)k;
    int hi = (int)(unsigned)(k >> 32);
    lo = __builtin_amdgcn_update_dpp(0, lo, CTRL, 0xF, 0xF, true);
    hi = __builtin_amdgcn_update_dpp(0, hi, CTRL, 0xF, 0xF, true);
    return ((unsigned long long)(unsigned)hi << 32) | (unsigned)lo;
}

__device__ __forceinline__ unsigned long long umin64(unsigned long long a,
                                                     unsigned long long b) {
    return a < b ? a : b;   // v_cmp_lt_u64 + 2 cndmask
}

__global__ __launch_bounds__(256, 8)
void energy_well_kernel(const float2* __restrict__ inst_pos,   // N
                        const float2* __restrict__ half_sizes, // N
                        const float*  __restrict__ well_boxes, // 64*4 {xl,yl,xh,yh}
                        const int4*   __restrict__ avail4,     // N*16
                        const float*  __restrict__ exponents,  // N
                        float* __restrict__ out,               // N
                        int N, int nT16)
{
    const int lane = threadIdx.x & 63;
    const int sub  = lane & 3;                 // quad member: wells [16sub,16sub+16)
    const int tile = (int)((blockIdx.x * blockDim.x + threadIdx.x) >> 6);
    if (tile >= nT16) return;

    const int i  = tile * 16 + (lane >> 2);    // this quad's instance
    const int ii = i < N ? i : N - 1;          // clamp (tail safety)

    // ---- issue all loads up front (7 VMEM, independent) ----
    const int4* a = avail4 + ((size_t)ii * 16 + (size_t)sub * 4);
    const int4 av0 = a[0], av1 = a[1], av2 = a[2], av3 = a[3];
    const float2 p = inst_pos[ii];
    const float2 h = half_sizes[ii];
    const float  e = exponents[ii];

    // x-edges: wave-uniform, compile-time offsets -> s_load (stay in SGPRs)
    float xlv[8], xhv[8];
    #pragma unroll
    for (int ix = 0; ix < 8; ++ix) {
        xlv[ix] = well_boxes[4 * ix + 0];
        xhv[ix] = well_boxes[4 * ix + 2];
    }
    // this lane's two y-rows (iy = 2*sub, 2*sub+1)
    const float ylA = well_boxes[64 * sub + 1];
    const float yhA = well_boxes[64 * sub + 3];
    const float ylB = well_boxes[64 * sub + 33];
    const float yhB = well_boxes[64 * sub + 35];

    // ---- per-instance separable distances ----
    const float xm = p.x - h.x, xp_ = p.x + h.x;
    const float ym = p.y - h.y, yp_ = p.y + h.y;

    float dxv[8];
    #pragma unroll
    for (int ix = 0; ix < 8; ++ix)
        dxv[ix] = fmaxf(fmaxf(xlv[ix] - xm, xp_ - xhv[ix]), 0.0f);  // v_max3
    const float dyA = fmaxf(fmaxf(ylA - ym, yp_ - yhA), 0.0f);
    const float dyB = fmaxf(fmaxf(ylB - ym, yp_ - yhB), 0.0f);

    // ---- keyed scan: 2 independent chains of 8, then merge (register-lean) ----
    const unsigned gbase = (unsigned)(sub << 4);
    unsigned long long acc0 = ~0ull, acc1 = ~0ull;
    #pragma unroll
    for (int j = 0; j < 4; ++j) {
        const int4 a4 = (j == 0) ? av0 : (j == 1) ? av1 : (j == 2) ? av2 : av3;
        #pragma unroll
        for (int k = 0; k < 4; ++k) {
            const int c2 = 4 * j + k;                   // local well 0..15
            const int avw = (k == 0) ? a4.x : (k == 1) ? a4.y
                          : (k == 2) ? a4.z : a4.w;
            const float dy   = (c2 < 8) ? dyA : dyB;
            const float dist = dxv[c2 & 7] + dy;
            unsigned long long key =
                (((unsigned long long)__float_as_uint(dist)) << 6)
                | (unsigned long long)(gbase + (unsigned)c2);
            key = avw ? key : ~0ull;                    // mask unavailable
            if (c2 & 1) acc1 = umin64(acc1, key);       // 2 parallel chains
            else        acc0 = umin64(acc0, key);
        }
    }
    unsigned long long kmin = umin64(acc0, acc1);

    // ---- cross-sub (quad) reduce on the VALU pipe via DPP ----
    kmin = umin64(kmin, dpp64<0xB1>(kmin));   // quad_perm [1,0,3,2] : xor 1
    kmin = umin64(kmin, dpp64<0x4E>(kmin));   // quad_perm [2,3,0,1] : xor 2

    // ---- decode winner and store ----
    const int g = (int)(kmin & 63);           // global well index of the min
    const int s = g & 7;                      // ix
    float a0 = (s & 1) ? dxv[1] : dxv[0];
    float a1 = (s & 1) ? dxv[3] : dxv[2];
    float a2 = (s & 1) ? dxv[5] : dxv[4];
    float a3 = (s & 1) ? dxv[7] : dxv[6];
    float b0 = (s & 2) ? a1 : a0;
    float b1 = (s & 2) ? a3 : a2;
    const float dxs = (s & 4) ? b1 : b0;
    const float dys = (g & 8) ? dyB : dyA;    // valid on the winner's sub

    if (((g >> 4) == sub) && (i < N)) {       // unique winner lane per quad
        float energy;
        if (e == 2.0f) energy = dxs * dxs + dys * dys;
        else           energy = powf(dxs, e) + powf(dys, e);
        out[i] = energy;
    }
}

extern "C" void kernel_launch(void* const* d_in, const int* in_sizes, int n_in,
                              void* d_out, int out_size, void* d_ws, size_t ws_size,
                              hipStream_t stream)
{
    // 0: inst_pos (N*2 f32), 1: half_inst_sizes (N*2 f32), 2: inst_areas (UNUSED),
    // 3: well_boxes (64*4 f32), 4: inst_cr_avail_map (N*64 int), 5: exponents (N)
    const float2* inst_pos   = (const float2*)d_in[0];
    const float2* half_sizes = (const float2*)d_in[1];
    const float*  well_boxes = (const float*)d_in[3];
    const int4*   avail4     = (const int4*)d_in[4];
    const float*  exponents  = (const float*)d_in[5];
    float* out = (float*)d_out;

    const int N = in_sizes[5];
    const int nT16 = (N + 15) / 16;            // one 16-instance tile per wave
    const int blocks = (nT16 + 3) / 4;         // 4 waves/block

    energy_well_kernel<<<dim3(blocks), dim3(256), 0, stream>>>(
        inst_pos, half_sizes, well_boxes, avail4, exponents, out, N, nT16);
}